// Round 3
// baseline (12373.688 us; speedup 1.0000x reference)
//
#include <hip/hip_runtime.h>

#define T_ 2048
#define B_ 128
#define IN_ 64
#define H_ 128
#define OUT_ 32

typedef _Float16 half8 __attribute__((ext_vector_type(8)));
typedef float float4v __attribute__((ext_vector_type(4)));

#define XSTR 144            // bytes per batch-row in sh_x (16B aligned, conflict-min)
#define GSTR 260            // dwords per batch-row in sh_g (stride 4 mod 32 banks)
// d_ws layout
#define H0_OFF 0            // _Float16 [4 slots][8 g][16 n][128 k]
#define H1_OFF 131072
#define F_OFF  262144       // int [8 g][4 r]

union HU2 { unsigned u; _Float16 h[2]; };

__device__ __forceinline__ float sigm(float x) { return 1.0f / (1.0f + __expf(-x)); }
__device__ __forceinline__ float tanh_f(float x) { return 1.0f - 2.0f / (1.0f + __expf(2.0f * x)); }

__device__ __forceinline__ half8 make_afrag(const float* __restrict__ W, int K, int row, int col) {
  const float* p = W + (size_t)row * K + col;
  float4 a = *(const float4*)p;
  float4 b = *(const float4*)(p + 4);
  half8 h;
  h[0]=(_Float16)a.x; h[1]=(_Float16)a.y; h[2]=(_Float16)a.z; h[3]=(_Float16)a.w;
  h[4]=(_Float16)b.x; h[5]=(_Float16)b.y; h[6]=(_Float16)b.z; h[7]=(_Float16)b.w;
  return h;
}

__device__ __forceinline__ int fwait_ge(int* p, int want) {
  while (__hip_atomic_load(p, __ATOMIC_RELAXED, __HIP_MEMORY_SCOPE_AGENT) < want)
    __builtin_amdgcn_s_sleep(1);
  return 0;
}

__global__ __launch_bounds__(512, 2) void lstm_pipe(
    const float* __restrict__ x, const float* __restrict__ w_ih0,
    const float* __restrict__ w_hh0, const float* __restrict__ w_ih1,
    const float* __restrict__ w_hh1, const float* __restrict__ fc_w,
    const float* __restrict__ fc_b, float* __restrict__ out, char* __restrict__ ws)
{
  const int tid = threadIdx.x, lane = tid & 63, w = tid >> 6;
  const int quad = lane >> 4, n = lane & 15;
  const int g = blockIdx.x & 7, r = blockIdx.x >> 3;   // group-per-XCD affinity
  const int hh = (r < 2) ? r : (r - 2);                // H-half (64 rows)
  const int gt = w >> 1, sb = w & 1;                   // gate, sub-tile base
  _Float16* Hb0 = (_Float16*)(ws + H0_OFF);
  _Float16* Hb1 = (_Float16*)(ws + H1_OFF);
  int* F = (int*)(ws + F_OFF);

  __shared__ char  sh_x[16 * XSTR];
  __shared__ float sh_g[16 * GSTR];

  const int cn = tid >> 5, cr2 = (tid & 31) * 2;       // c-thread: batch col, row pair
  float c_a = 0.f, c_b = 0.f, hva = 0.f, hvb = 0.f;
  const size_t hn_base = (size_t)T_ * B_ * OUT_;

  if (r < 2) {
    // ======================= LAYER 0 =======================
    half8 a_x[2][2], a_h[2][4];
#pragma unroll
    for (int s2 = 0; s2 < 2; ++s2) {
      const int row = gt * H_ + hh * 64 + (sb + 2 * s2) * 16 + n;
#pragma unroll
      for (int kt = 0; kt < 2; ++kt) a_x[s2][kt] = make_afrag(w_ih0, IN_, row, kt * 32 + quad * 8);
#pragma unroll
      for (int kt = 0; kt < 4; ++kt) a_h[s2][kt] = make_afrag(w_hh0, H_, row, kt * 32 + quad * 8);
    }
    {
      const int xn = tid >> 5, xk = tid & 31;
      float2 xv = *(const float2*)(x + ((size_t)0 * B_ + g * 16 + xn) * IN_ + xk * 2);
      HU2 u; u.h[0] = (_Float16)xv.x; u.h[1] = (_Float16)xv.y;
      *(unsigned*)(sh_x + xn * XSTR + xk * 4) = u.u;
    }
    __syncthreads();

    int* Fpeer = &F[g * 4 + (1 - hh)];
    int* Fl1 = &F[g * 4 + 2];

    for (int t = 0; t < T_; ++t) {
      const bool hx = (t + 1 < T_);
      const int xn = tid >> 5, xk = tid & 31;
      float2 xvn = make_float2(0.f, 0.f);
      if (hx) xvn = *(const float2*)(x + ((size_t)(t + 1) * B_ + g * 16 + xn) * IN_ + xk * 2);

      float4v acc0 = {0.f,0.f,0.f,0.f}, acc1 = {0.f,0.f,0.f,0.f};
#pragma unroll
      for (int kt = 0; kt < 2; ++kt) {          // x-part first: no cross-block dependency
        half8 Bx = *(const half8*)(sh_x + n * XSTR + (kt * 32 + quad * 8) * 2);
        acc0 = __builtin_amdgcn_mfma_f32_16x16x32_f16(a_x[0][kt], Bx, acc0, 0, 0, 0);
        acc1 = __builtin_amdgcn_mfma_f32_16x16x32_f16(a_x[1][kt], Bx, acc1, 0, 0, 0);
      }
      if (t > 0) {
        fwait_ge(Fpeer, t);                     // peer h0(t-1) published
        __builtin_amdgcn_fence(__ATOMIC_ACQUIRE, "agent");
        const _Float16* hp = Hb0 + (((size_t)((t - 1) & 3) * 8 + g) * 16 + n) * 128;
#pragma unroll
        for (int kt = 0; kt < 4; ++kt) {
          half8 Bh = *(const half8*)(hp + kt * 32 + quad * 8);
          acc0 = __builtin_amdgcn_mfma_f32_16x16x32_f16(a_h[0][kt], Bh, acc0, 0, 0, 0);
          acc1 = __builtin_amdgcn_mfma_f32_16x16x32_f16(a_h[1][kt], Bh, acc1, 0, 0, 0);
        }
      }
      {
        float4v A0 = acc0, A1 = acc1;
        float4 av0, av1;
        if (gt == 2) {
          av0 = make_float4(tanh_f(A0[0]), tanh_f(A0[1]), tanh_f(A0[2]), tanh_f(A0[3]));
          av1 = make_float4(tanh_f(A1[0]), tanh_f(A1[1]), tanh_f(A1[2]), tanh_f(A1[3]));
        } else {
          av0 = make_float4(sigm(A0[0]), sigm(A0[1]), sigm(A0[2]), sigm(A0[3]));
          av1 = make_float4(sigm(A1[0]), sigm(A1[1]), sigm(A1[2]), sigm(A1[3]));
        }
        *(float4*)(&sh_g[n * GSTR + gt * 64 + sb * 16 + quad * 4]) = av0;
        *(float4*)(&sh_g[n * GSTR + gt * 64 + (sb + 2) * 16 + quad * 4]) = av1;
      }
      __syncthreads();
      if (t >= 4) {                              // back-pressure: L1 done reading h0(t-4)
        fwait_ge(&Fl1[0], t - 3);
        fwait_ge(&Fl1[1], t - 3);
      }
      {
        const float* gp = &sh_g[cn * GSTR];
        float2 iv = *(const float2*)(gp + cr2);
        float2 fv = *(const float2*)(gp + 64 + cr2);
        float2 gv = *(const float2*)(gp + 128 + cr2);
        float2 ov = *(const float2*)(gp + 192 + cr2);
        c_a = fv.x * c_a + iv.x * gv.x; hva = ov.x * tanh_f(c_a);
        c_b = fv.y * c_b + iv.y * gv.y; hvb = ov.y * tanh_f(c_b);
        HU2 u; u.h[0] = (_Float16)hva; u.h[1] = (_Float16)hvb;
        *(unsigned*)(Hb0 + (((size_t)(t & 3) * 8 + g) * 16 + cn) * 128 + hh * 64 + cr2) = u.u;
      }
      if (hx) {
        HU2 u; u.h[0] = (_Float16)xvn.x; u.h[1] = (_Float16)xvn.y;
        *(unsigned*)(sh_x + xn * XSTR + xk * 4) = u.u;
      }
      __syncthreads();                           // drains vmcnt: all h stores complete
      if (tid == 0) {
        __builtin_amdgcn_fence(__ATOMIC_RELEASE, "agent");
        __hip_atomic_store(&F[g * 4 + hh], t + 1, __ATOMIC_RELAXED, __HIP_MEMORY_SCOPE_AGENT);
      }
    }
    {
      float* hn = out + hn_base;
      float* cnp = out + hn_base + 2 * (size_t)B_ * H_;
      size_t idx = (size_t)(g * 16 + cn) * H_ + hh * 64 + cr2;
      *(float2*)(hn + idx) = make_float2(hva, hvb);
      *(float2*)(cnp + idx) = make_float2(c_a, c_b);
    }
  } else {
    // ======================= LAYER 1 + FC =======================
    half8 a_i[2][4], a_h[2][4], a_fc[4];
#pragma unroll
    for (int s2 = 0; s2 < 2; ++s2) {
      const int row = gt * H_ + hh * 64 + (sb + 2 * s2) * 16 + n;
#pragma unroll
      for (int kt = 0; kt < 4; ++kt) {
        a_i[s2][kt] = make_afrag(w_ih1, H_, row, kt * 32 + quad * 8);
        a_h[s2][kt] = make_afrag(w_hh1, H_, row, kt * 32 + quad * 8);
      }
    }
#pragma unroll
    for (int kt = 0; kt < 4; ++kt) a_fc[kt] = make_afrag(fc_w, H_, hh * 16 + n, kt * 32 + quad * 8);
    const float4 fb = *(const float4*)(fc_b + hh * 16 + quad * 4);

    int* Fpeer = &F[g * 4 + 2 + (1 - hh)];
    int* F0p = &F[g * 4];

    for (int t = 0; t < T_; ++t) {
      float4v acc0 = {0.f,0.f,0.f,0.f}, acc1 = {0.f,0.f,0.f,0.f};
      if (t > 0) {
        fwait_ge(Fpeer, t);                      // peer h1(t-1)
        __builtin_amdgcn_fence(__ATOMIC_ACQUIRE, "agent");
        const _Float16* hp = Hb1 + (((size_t)((t - 1) & 3) * 8 + g) * 16 + n) * 128;
        half8 Bh[4];
#pragma unroll
        for (int kt = 0; kt < 4; ++kt) Bh[kt] = *(const half8*)(hp + kt * 32 + quad * 8);
        if (w == 0) {                            // FC(t-1), reusing h1(t-1) fragments
          float4v af = {0.f,0.f,0.f,0.f};
#pragma unroll
          for (int kt = 0; kt < 4; ++kt)
            af = __builtin_amdgcn_mfma_f32_16x16x32_f16(a_fc[kt], Bh[kt], af, 0, 0, 0);
          float* op = out + ((size_t)(t - 1) * B_ + g * 16 + n) * OUT_ + hh * 16 + quad * 4;
          *(float4*)op = make_float4(af[0]+fb.x, af[1]+fb.y, af[2]+fb.z, af[3]+fb.w);
        }
#pragma unroll
        for (int kt = 0; kt < 4; ++kt) {
          acc0 = __builtin_amdgcn_mfma_f32_16x16x32_f16(a_h[0][kt], Bh[kt], acc0, 0, 0, 0);
          acc1 = __builtin_amdgcn_mfma_f32_16x16x32_f16(a_h[1][kt], Bh[kt], acc1, 0, 0, 0);
        }
      }
      fwait_ge(&F0p[0], t + 1);                  // h0(t) both halves (same-step edge)
      fwait_ge(&F0p[1], t + 1);
      __builtin_amdgcn_fence(__ATOMIC_ACQUIRE, "agent");
      {
        const _Float16* hp = Hb0 + (((size_t)(t & 3) * 8 + g) * 16 + n) * 128;
#pragma unroll
        for (int kt = 0; kt < 4; ++kt) {
          half8 B0 = *(const half8*)(hp + kt * 32 + quad * 8);
          acc0 = __builtin_amdgcn_mfma_f32_16x16x32_f16(a_i[0][kt], B0, acc0, 0, 0, 0);
          acc1 = __builtin_amdgcn_mfma_f32_16x16x32_f16(a_i[1][kt], B0, acc1, 0, 0, 0);
        }
      }
      {
        float4v A0 = acc0, A1 = acc1;
        float4 av0, av1;
        if (gt == 2) {
          av0 = make_float4(tanh_f(A0[0]), tanh_f(A0[1]), tanh_f(A0[2]), tanh_f(A0[3]));
          av1 = make_float4(tanh_f(A1[0]), tanh_f(A1[1]), tanh_f(A1[2]), tanh_f(A1[3]));
        } else {
          av0 = make_float4(sigm(A0[0]), sigm(A0[1]), sigm(A0[2]), sigm(A0[3]));
          av1 = make_float4(sigm(A1[0]), sigm(A1[1]), sigm(A1[2]), sigm(A1[3]));
        }
        *(float4*)(&sh_g[n * GSTR + gt * 64 + sb * 16 + quad * 4]) = av0;
        *(float4*)(&sh_g[n * GSTR + gt * 64 + (sb + 2) * 16 + quad * 4]) = av1;
      }
      __syncthreads();
      {
        const float* gp = &sh_g[cn * GSTR];
        float2 iv = *(const float2*)(gp + cr2);
        float2 fv = *(const float2*)(gp + 64 + cr2);
        float2 gv = *(const float2*)(gp + 128 + cr2);
        float2 ov = *(const float2*)(gp + 192 + cr2);
        c_a = fv.x * c_a + iv.x * gv.x; hva = ov.x * tanh_f(c_a);
        c_b = fv.y * c_b + iv.y * gv.y; hvb = ov.y * tanh_f(c_b);
        HU2 u; u.h[0] = (_Float16)hva; u.h[1] = (_Float16)hvb;
        *(unsigned*)(Hb1 + (((size_t)(t & 3) * 8 + g) * 16 + cn) * 128 + hh * 64 + cr2) = u.u;
      }
      __syncthreads();
      if (tid == 0) {
        __builtin_amdgcn_fence(__ATOMIC_RELEASE, "agent");
        __hip_atomic_store(&F[g * 4 + 2 + hh], t + 1, __ATOMIC_RELAXED, __HIP_MEMORY_SCOPE_AGENT);
      }
    }
    // FC for t = T-1
    fwait_ge(Fpeer, T_);
    __builtin_amdgcn_fence(__ATOMIC_ACQUIRE, "agent");
    if (w == 0) {
      const _Float16* hp = Hb1 + (((size_t)((T_ - 1) & 3) * 8 + g) * 16 + n) * 128;
      float4v af = {0.f,0.f,0.f,0.f};
#pragma unroll
      for (int kt = 0; kt < 4; ++kt) {
        half8 Bh = *(const half8*)(hp + kt * 32 + quad * 8);
        af = __builtin_amdgcn_mfma_f32_16x16x32_f16(a_fc[kt], Bh, af, 0, 0, 0);
      }
      float* op = out + ((size_t)(T_ - 1) * B_ + g * 16 + n) * OUT_ + hh * 16 + quad * 4;
      *(float4*)op = make_float4(af[0]+fb.x, af[1]+fb.y, af[2]+fb.z, af[3]+fb.w);
    }
    {
      float* hn = out + hn_base + (size_t)B_ * H_;
      float* cnp = out + hn_base + 3 * (size_t)B_ * H_;
      size_t idx = (size_t)(g * 16 + cn) * H_ + hh * 64 + cr2;
      *(float2*)(hn + idx) = make_float2(hva, hvb);
      *(float2*)(cnp + idx) = make_float2(c_a, c_b);
    }
  }
}

extern "C" void kernel_launch(void* const* d_in, const int* in_sizes, int n_in,
                              void* d_out, int out_size, void* d_ws, size_t ws_size,
                              hipStream_t stream) {
  const float* x     = (const float*)d_in[0];
  const float* w_ih0 = (const float*)d_in[1];
  const float* w_hh0 = (const float*)d_in[2];
  const float* w_ih1 = (const float*)d_in[3];
  const float* w_hh1 = (const float*)d_in[4];
  const float* fc_w  = (const float*)d_in[5];
  const float* fc_b  = (const float*)d_in[6];
  lstm_pipe<<<32, 512, 0, stream>>>(x, w_ih0, w_hh0, w_ih1, w_hh1, fc_w, fc_b,
                                    (float*)d_out, (char*)d_ws);
}

// Round 4
// 4595.662 us; speedup vs baseline: 2.6925x; 2.6925x over previous
//
#include <hip/hip_runtime.h>

#define T_ 2048
#define B_ 128
#define IN_ 64
#define H_ 128
#define OUT_ 32
#define CH_ 32          // steps per ring chunk (sync amortization)
#define RING_ 2         // chunks in flight

typedef _Float16 half8 __attribute__((ext_vector_type(8)));
typedef _Float16 half4v __attribute__((ext_vector_type(4)));
typedef float float4v __attribute__((ext_vector_type(4)));

#define XSTR 144        // bytes per batch-row, x staging (16B-aligned)
#define HSTR 272        // bytes per batch-row, h staging (17*16B)
// d_ws: y0 ring [8 groups][RING_][CH_][16 n][128 k] f16, then int flag[8], consumed[8]
#define GRP_ELEMS ((size_t)RING_ * CH_ * 16 * 128)
#define RING_BYTES ((size_t)8 * GRP_ELEMS * 2)

__device__ __forceinline__ float sigm(float x) { return 1.0f / (1.0f + __expf(-x)); }
__device__ __forceinline__ float tanh_f(float x) { return 1.0f - 2.0f / (1.0f + __expf(2.0f * x)); }

__device__ __forceinline__ half8 make_afrag(const float* __restrict__ W, int K, int row, int col) {
  const float* p = W + (size_t)row * K + col;
  float4 a = *(const float4*)p;
  float4 b = *(const float4*)(p + 4);
  half8 h;
  h[0]=(_Float16)a.x; h[1]=(_Float16)a.y; h[2]=(_Float16)a.z; h[3]=(_Float16)a.w;
  h[4]=(_Float16)b.x; h[5]=(_Float16)b.y; h[6]=(_Float16)b.z; h[7]=(_Float16)b.w;
  return h;
}

__device__ __forceinline__ void wait_ge(int* p, int want) {
  while (__hip_atomic_load(p, __ATOMIC_RELAXED, __HIP_MEMORY_SCOPE_AGENT) < want)
    __builtin_amdgcn_s_sleep(2);
}

__global__ void ring_init(int* f) { if (threadIdx.x < 16) f[threadIdx.x] = 0; }

__global__ __launch_bounds__(512, 2) void lstm_wavefront(
    const float* __restrict__ x, const float* __restrict__ w_ih0,
    const float* __restrict__ w_hh0, const float* __restrict__ w_ih1,
    const float* __restrict__ w_hh1, const float* __restrict__ fc_w,
    const float* __restrict__ fc_b, float* __restrict__ out, char* __restrict__ ws)
{
  const int tid  = threadIdx.x, lane = tid & 63, w = tid >> 6;
  const int quad = lane >> 4, n = lane & 15;
  const int g = blockIdx.x & 7, layer = blockIdx.x >> 3;  // pair per XCD
  _Float16* ring = (_Float16*)ws + (size_t)g * GRP_ELEMS;
  int* flag     = (int*)(ws + RING_BYTES) + g;        // chunks produced by L0
  int* consumed = (int*)(ws + RING_BYTES) + 8 + g;    // chunks consumed by L1

  __shared__ char sh_x[2 * 16 * XSTR];
  __shared__ char sh_h[2 * 16 * HSTR];

  const size_t hn_base = (size_t)T_ * B_ * OUT_;
  float4v c = {0.f, 0.f, 0.f, 0.f};
  float hf[4] = {0.f, 0.f, 0.f, 0.f};

  // zero h double-buffers (h(-1) = 0)
  for (int i = tid; i < 2 * 16 * HSTR / 4; i += 512) ((unsigned*)sh_h)[i] = 0u;

  if (layer == 0) {
    // ================= LAYER 0 (producer) =================
    half8 a_x[4][2], a_h[4][4];
#pragma unroll
    for (int gt = 0; gt < 4; ++gt) {
      const int row = gt * H_ + w * 16 + n;
#pragma unroll
      for (int kt = 0; kt < 2; ++kt) a_x[gt][kt] = make_afrag(w_ih0, IN_, row, kt * 32 + quad * 8);
#pragma unroll
      for (int kt = 0; kt < 4; ++kt) a_h[gt][kt] = make_afrag(w_hh0, H_, row, kt * 32 + quad * 8);
    }
    // stage x(0)
    {
      const int xn = tid >> 5, xk = (tid & 31) * 2;
      float2 xv = *(const float2*)(x + ((size_t)0 * B_ + g * 16 + xn) * IN_ + xk);
      _Float16* d = (_Float16*)(sh_x + xn * XSTR + xk * 2);
      d[0] = (_Float16)xv.x; d[1] = (_Float16)xv.y;
    }
    __syncthreads();
    int p = 0;

    for (int t = 0; t < T_; ++t) {
      const int ck = t / CH_, s = t % CH_;
      if (s == 0 && ck >= RING_) {             // back-pressure on ring slot
        if (tid == 0) wait_ge(consumed, ck - (RING_ - 1));
        __syncthreads();
      }
      // prefetch x(t+1)
      const int xn = tid >> 5, xk = (tid & 31) * 2;
      float2 xv = make_float2(0.f, 0.f);
      if (t + 1 < T_) xv = *(const float2*)(x + ((size_t)(t + 1) * B_ + g * 16 + xn) * IN_ + xk);

      float4v acc[4] = {{0,0,0,0},{0,0,0,0},{0,0,0,0},{0,0,0,0}};
#pragma unroll
      for (int kt = 0; kt < 2; ++kt) {
        half8 Bx = *(const half8*)(sh_x + (t & 1) * 16 * XSTR + n * XSTR + (kt * 32 + quad * 8) * 2);
#pragma unroll
        for (int gt = 0; gt < 4; ++gt)
          acc[gt] = __builtin_amdgcn_mfma_f32_16x16x32_f16(a_x[gt][kt], Bx, acc[gt], 0, 0, 0);
      }
#pragma unroll
      for (int kt = 0; kt < 4; ++kt) {
        half8 Bh = *(const half8*)(sh_h + p * 16 * HSTR + n * HSTR + (kt * 32 + quad * 8) * 2);
#pragma unroll
        for (int gt = 0; gt < 4; ++gt)
          acc[gt] = __builtin_amdgcn_mfma_f32_16x16x32_f16(a_h[gt][kt], Bh, acc[gt], 0, 0, 0);
      }
      half4v hh;
#pragma unroll
      for (int r = 0; r < 4; ++r) {
        float iv = sigm(acc[0][r]), fv = sigm(acc[1][r]);
        float gv = tanh_f(acc[2][r]), ov = sigm(acc[3][r]);
        c[r] = fv * c[r] + iv * gv;
        hf[r] = ov * tanh_f(c[r]);
        hh[r] = (_Float16)hf[r];
      }
      // publish h0(t): LDS (for next step) + y0 ring (for L1)
      *(half4v*)(sh_h + (1 - p) * 16 * HSTR + n * HSTR + (w * 16 + quad * 4) * 2) = hh;
      *(half4v*)(ring + ((size_t)((ck % RING_) * CH_ + s) * 16 + n) * 128 + w * 16 + quad * 4) = hh;
      if (t + 1 < T_) {
        _Float16* d = (_Float16*)(sh_x + ((t + 1) & 1) * 16 * XSTR + xn * XSTR + xk * 2);
        d[0] = (_Float16)xv.x; d[1] = (_Float16)xv.y;
      }
      __syncthreads();                          // drains LDS + global stores
      if (s == CH_ - 1 && tid == 0) {
        __builtin_amdgcn_fence(__ATOMIC_RELEASE, "agent");
        __hip_atomic_store(flag, ck + 1, __ATOMIC_RELAXED, __HIP_MEMORY_SCOPE_AGENT);
      }
      p ^= 1;
    }
    // final states h0_n, c0_n (f32)
    {
      float* hn = out + hn_base;
      float* cn = out + hn_base + 2 * (size_t)B_ * H_;
      size_t idx = (size_t)(g * 16 + n) * H_ + w * 16 + quad * 4;
      *(float4*)(hn + idx) = make_float4(hf[0], hf[1], hf[2], hf[3]);
      *(float4*)(cn + idx) = make_float4(c[0], c[1], c[2], c[3]);
    }
  } else {
    // ================= LAYER 1 + FC (consumer) =================
    half8 a_i[4][4], a_h[4][4], a_fc[4];
#pragma unroll
    for (int gt = 0; gt < 4; ++gt) {
      const int row = gt * H_ + w * 16 + n;
#pragma unroll
      for (int kt = 0; kt < 4; ++kt) {
        a_i[gt][kt] = make_afrag(w_ih1, H_, row, kt * 32 + quad * 8);
        a_h[gt][kt] = make_afrag(w_hh1, H_, row, kt * 32 + quad * 8);
      }
    }
    float4 fb = make_float4(0.f, 0.f, 0.f, 0.f);
    if (w < 2) {
#pragma unroll
      for (int kt = 0; kt < 4; ++kt) a_fc[kt] = make_afrag(fc_w, H_, w * 16 + n, kt * 32 + quad * 8);
      fb = *(const float4*)(fc_b + w * 16 + quad * 4);
    }
    __syncthreads();
    int q = 0;

    for (int t = 0; t < T_; ++t) {
      const int ck = t / CH_, s = t % CH_;
      if (s == 0) {                            // chunk available?
        if (tid == 0) wait_ge(flag, ck + 1);
        __syncthreads();
        __builtin_amdgcn_fence(__ATOMIC_ACQUIRE, "agent");
      }
      // y0(t) B-fragments straight from ring (L2-resident)
      half8 By[4];
      {
        const _Float16* yp = ring + ((size_t)((ck % RING_) * CH_ + s) * 16 + n) * 128 + quad * 8;
#pragma unroll
        for (int kt = 0; kt < 4; ++kt) By[kt] = *(const half8*)(yp + kt * 32);
      }
      // h1(t-1) fragments from LDS; FC(t-1) reuses them
      half8 Bh[4];
#pragma unroll
      for (int kt = 0; kt < 4; ++kt)
        Bh[kt] = *(const half8*)(sh_h + q * 16 * HSTR + n * HSTR + (kt * 32 + quad * 8) * 2);
      if (w < 2 && t > 0) {
        float4v af = {0.f, 0.f, 0.f, 0.f};
#pragma unroll
        for (int kt = 0; kt < 4; ++kt)
          af = __builtin_amdgcn_mfma_f32_16x16x32_f16(a_fc[kt], Bh[kt], af, 0, 0, 0);
        float* op = out + ((size_t)(t - 1) * B_ + g * 16 + n) * OUT_ + w * 16 + quad * 4;
        *(float4*)op = make_float4(af[0] + fb.x, af[1] + fb.y, af[2] + fb.z, af[3] + fb.w);
      }
      float4v acc[4] = {{0,0,0,0},{0,0,0,0},{0,0,0,0},{0,0,0,0}};
#pragma unroll
      for (int kt = 0; kt < 4; ++kt) {
#pragma unroll
        for (int gt = 0; gt < 4; ++gt)
          acc[gt] = __builtin_amdgcn_mfma_f32_16x16x32_f16(a_h[gt][kt], Bh[kt], acc[gt], 0, 0, 0);
      }
#pragma unroll
      for (int kt = 0; kt < 4; ++kt) {
#pragma unroll
        for (int gt = 0; gt < 4; ++gt)
          acc[gt] = __builtin_amdgcn_mfma_f32_16x16x32_f16(a_i[gt][kt], By[kt], acc[gt], 0, 0, 0);
      }
      half4v hh;
#pragma unroll
      for (int r = 0; r < 4; ++r) {
        float iv = sigm(acc[0][r]), fv = sigm(acc[1][r]);
        float gv = tanh_f(acc[2][r]), ov = sigm(acc[3][r]);
        c[r] = fv * c[r] + iv * gv;
        hf[r] = ov * tanh_f(c[r]);
        hh[r] = (_Float16)hf[r];
      }
      *(half4v*)(sh_h + (1 - q) * 16 * HSTR + n * HSTR + (w * 16 + quad * 4) * 2) = hh;
      __syncthreads();
      if (s == CH_ - 1 && tid == 0) {
        __builtin_amdgcn_fence(__ATOMIC_RELEASE, "agent");
        __hip_atomic_store(consumed, ck + 1, __ATOMIC_RELAXED, __HIP_MEMORY_SCOPE_AGENT);
      }
      q ^= 1;
    }
    // FC(T-1) from sh_h[q] = h1(T-1)
    if (w < 2) {
      float4v af = {0.f, 0.f, 0.f, 0.f};
#pragma unroll
      for (int kt = 0; kt < 4; ++kt) {
        half8 Bh = *(const half8*)(sh_h + q * 16 * HSTR + n * HSTR + (kt * 32 + quad * 8) * 2);
        af = __builtin_amdgcn_mfma_f32_16x16x32_f16(a_fc[kt], Bh, af, 0, 0, 0);
      }
      float* op = out + ((size_t)(T_ - 1) * B_ + g * 16 + n) * OUT_ + w * 16 + quad * 4;
      *(float4*)op = make_float4(af[0] + fb.x, af[1] + fb.y, af[2] + fb.z, af[3] + fb.w);
    }
    {
      float* hn = out + hn_base + (size_t)B_ * H_;
      float* cn = out + hn_base + 3 * (size_t)B_ * H_;
      size_t idx = (size_t)(g * 16 + n) * H_ + w * 16 + quad * 4;
      *(float4*)(hn + idx) = make_float4(hf[0], hf[1], hf[2], hf[3]);
      *(float4*)(cn + idx) = make_float4(c[0], c[1], c[2], c[3]);
    }
  }
}

extern "C" void kernel_launch(void* const* d_in, const int* in_sizes, int n_in,
                              void* d_out, int out_size, void* d_ws, size_t ws_size,
                              hipStream_t stream) {
  const float* x     = (const float*)d_in[0];
  const float* w_ih0 = (const float*)d_in[1];
  const float* w_hh0 = (const float*)d_in[2];
  const float* w_ih1 = (const float*)d_in[3];
  const float* w_hh1 = (const float*)d_in[4];
  const float* fc_w  = (const float*)d_in[5];
  const float* fc_b  = (const float*)d_in[6];
  char* ws = (char*)d_ws;
  ring_init<<<1, 64, 0, stream>>>((int*)(ws + RING_BYTES));
  lstm_wavefront<<<16, 512, 0, stream>>>(x, w_ih0, w_hh0, w_ih1, w_hh1,
                                         fc_w, fc_b, (float*)d_out, ws);
}

// Round 5
// 3246.503 us; speedup vs baseline: 3.8114x; 1.4156x over previous
//
#include <hip/hip_runtime.h>

#define T_ 2048
#define B_ 128
#define IN_ 64
#define H_ 128
#define OUT_ 32
#define CH_ 32          // steps per ring chunk (sync amortization)
#define RING_ 2         // chunks in flight

typedef _Float16 half8 __attribute__((ext_vector_type(8)));
typedef _Float16 half4v __attribute__((ext_vector_type(4)));
typedef float float4v __attribute__((ext_vector_type(4)));

#define XSTR 144        // bytes per batch-row, x staging
#define HSTR 272        // bytes per batch-row, h staging
#define GRP_ELEMS ((size_t)RING_ * CH_ * 16 * 128)
#define RING_BYTES ((size_t)8 * GRP_ELEMS * 2)

// fast activations: v_exp_f32 + v_rcp_f32 (no IEEE div sequence)
__device__ __forceinline__ float sigm(float x) {
  return __builtin_amdgcn_rcpf(1.0f + __expf(-x));
}
__device__ __forceinline__ float tanh_f(float x) {
  return fmaf(-2.0f, __builtin_amdgcn_rcpf(1.0f + __expf(2.0f * x)), 1.0f);
}

__device__ __forceinline__ half8 make_afrag(const float* __restrict__ W, int K, int row, int col) {
  const float* p = W + (size_t)row * K + col;
  float4 a = *(const float4*)p;
  float4 b = *(const float4*)(p + 4);
  half8 h;
  h[0]=(_Float16)a.x; h[1]=(_Float16)a.y; h[2]=(_Float16)a.z; h[3]=(_Float16)a.w;
  h[4]=(_Float16)b.x; h[5]=(_Float16)b.y; h[6]=(_Float16)b.z; h[7]=(_Float16)b.w;
  return h;
}

__device__ __forceinline__ void wait_ge(int* p, int want) {
  while (__hip_atomic_load(p, __ATOMIC_RELAXED, __HIP_MEMORY_SCOPE_AGENT) < want)
    __builtin_amdgcn_s_sleep(2);
}

__global__ void ring_init(int* f) { if (threadIdx.x < 16) f[threadIdx.x] = 0; }

__global__ __launch_bounds__(512) void lstm_wavefront(
    const float* __restrict__ x, const float* __restrict__ w_ih0,
    const float* __restrict__ w_hh0, const float* __restrict__ w_ih1,
    const float* __restrict__ w_hh1, const float* __restrict__ fc_w,
    const float* __restrict__ fc_b, float* __restrict__ out, char* __restrict__ ws)
{
  const int tid  = threadIdx.x, lane = tid & 63, w = tid >> 6;
  const int quad = lane >> 4, n = lane & 15;
  const int g = blockIdx.x & 7, layer = blockIdx.x >> 3;  // L0/L1 pair per XCD
  _Float16* ring = (_Float16*)ws + (size_t)g * GRP_ELEMS;
  int* flag     = (int*)(ws + RING_BYTES) + g;        // chunks produced by L0
  int* consumed = (int*)(ws + RING_BYTES) + 8 + g;    // chunks consumed by L1

  __shared__ char sh_x[2 * 16 * XSTR];
  __shared__ char sh_h[2 * 16 * HSTR];

  const size_t hn_base = (size_t)T_ * B_ * OUT_;
  float4v c = {0.f, 0.f, 0.f, 0.f};
  float hf[4] = {0.f, 0.f, 0.f, 0.f};

  for (int i = tid; i < 2 * 16 * HSTR / 4; i += 512) ((unsigned*)sh_h)[i] = 0u;

  if (layer == 0) {
    // ================= LAYER 0 (producer) =================
    half8 a_x[4][2], a_h[4][4];
#pragma unroll
    for (int gt = 0; gt < 4; ++gt) {
      const int row = gt * H_ + w * 16 + n;
#pragma unroll
      for (int kt = 0; kt < 2; ++kt) a_x[gt][kt] = make_afrag(w_ih0, IN_, row, kt * 32 + quad * 8);
#pragma unroll
      for (int kt = 0; kt < 4; ++kt) a_h[gt][kt] = make_afrag(w_hh0, H_, row, kt * 32 + quad * 8);
    }
    {
      const int xn = tid >> 5, xk = (tid & 31) * 2;
      float2 xv = *(const float2*)(x + ((size_t)0 * B_ + g * 16 + xn) * IN_ + xk);
      _Float16* d = (_Float16*)(sh_x + xn * XSTR + xk * 2);
      d[0] = (_Float16)xv.x; d[1] = (_Float16)xv.y;
    }
    __syncthreads();
    int p = 0;
    half4v hh_def = {0, 0, 0, 0};

    for (int t = 0; t < T_; ++t) {
      const int ck = t / CH_, s = t - ck * CH_;
      if (s == 0 && ck >= RING_) {           // back-pressure on ring slot
        if (tid == 0) wait_ge(consumed, ck - 1);
        __syncthreads();
      }
      // deferred ring store of y0(t-1): store completes during this step's compute
      if (t > 0) {
        const int tp = t - 1;
        *(half4v*)(ring + ((size_t)(((tp / CH_) % RING_) * CH_ + (tp & (CH_ - 1))) * 16 + n) * 128
                   + w * 16 + quad * 4) = hh_def;
      }
      const int xn = tid >> 5, xk = (tid & 31) * 2;
      float2 xv = make_float2(0.f, 0.f);
      if (t + 1 < T_) xv = *(const float2*)(x + ((size_t)(t + 1) * B_ + g * 16 + xn) * IN_ + xk);

      float4v accA[4] = {{0,0,0,0},{0,0,0,0},{0,0,0,0},{0,0,0,0}};
      float4v accB[4] = {{0,0,0,0},{0,0,0,0},{0,0,0,0},{0,0,0,0}};
#pragma unroll
      for (int kt = 0; kt < 2; ++kt) {
        half8 Bx = *(const half8*)(sh_x + (t & 1) * 16 * XSTR + n * XSTR + (kt * 32 + quad * 8) * 2);
#pragma unroll
        for (int gt = 0; gt < 4; ++gt)
          accA[gt] = __builtin_amdgcn_mfma_f32_16x16x32_f16(a_x[gt][kt], Bx, accA[gt], 0, 0, 0);
      }
#pragma unroll
      for (int kt = 0; kt < 4; ++kt) {
        half8 Bh = *(const half8*)(sh_h + p * 16 * HSTR + n * HSTR + (kt * 32 + quad * 8) * 2);
#pragma unroll
        for (int gt = 0; gt < 4; ++gt)
          accB[gt] = __builtin_amdgcn_mfma_f32_16x16x32_f16(a_h[gt][kt], Bh, accB[gt], 0, 0, 0);
      }
      half4v hh;
#pragma unroll
      for (int r = 0; r < 4; ++r) {
        float iv = sigm(accA[0][r] + accB[0][r]);
        float fv = sigm(accA[1][r] + accB[1][r]);
        float gv = tanh_f(accA[2][r] + accB[2][r]);
        float ov = sigm(accA[3][r] + accB[3][r]);
        c[r] = fv * c[r] + iv * gv;
        hf[r] = ov * tanh_f(c[r]);
        hh[r] = (_Float16)hf[r];
      }
      *(half4v*)(sh_h + (1 - p) * 16 * HSTR + n * HSTR + (w * 16 + quad * 4) * 2) = hh;
      hh_def = hh;
      if (t + 1 < T_) {
        _Float16* d = (_Float16*)(sh_x + ((t + 1) & 1) * 16 * XSTR + xn * XSTR + xk * 2);
        d[0] = (_Float16)xv.x; d[1] = (_Float16)xv.y;
      }
      __syncthreads();
      if (tid == 0 && s == 0 && t > 0) {     // chunks 0..ck-1 fully stored+drained
        __builtin_amdgcn_fence(__ATOMIC_RELEASE, "agent");
        __hip_atomic_store(flag, ck, __ATOMIC_RELAXED, __HIP_MEMORY_SCOPE_AGENT);
      }
      p ^= 1;
    }
    // epilogue: final y0(T-1) + flag 64
    {
      const int tp = T_ - 1;
      *(half4v*)(ring + ((size_t)(((tp / CH_) % RING_) * CH_ + (tp & (CH_ - 1))) * 16 + n) * 128
                 + w * 16 + quad * 4) = hh_def;
    }
    __syncthreads();
    if (tid == 0) {
      __builtin_amdgcn_fence(__ATOMIC_RELEASE, "agent");
      __hip_atomic_store(flag, T_ / CH_, __ATOMIC_RELAXED, __HIP_MEMORY_SCOPE_AGENT);
    }
    {
      float* hn = out + hn_base;
      float* cn = out + hn_base + 2 * (size_t)B_ * H_;
      size_t idx = (size_t)(g * 16 + n) * H_ + w * 16 + quad * 4;
      *(float4*)(hn + idx) = make_float4(hf[0], hf[1], hf[2], hf[3]);
      *(float4*)(cn + idx) = make_float4(c[0], c[1], c[2], c[3]);
    }
  } else {
    // ================= LAYER 1 + FC (consumer) =================
    half8 a_i[4][4], a_h[4][4], a_fc[4];
#pragma unroll
    for (int gt = 0; gt < 4; ++gt) {
      const int row = gt * H_ + w * 16 + n;
#pragma unroll
      for (int kt = 0; kt < 4; ++kt) {
        a_i[gt][kt] = make_afrag(w_ih1, H_, row, kt * 32 + quad * 8);
        a_h[gt][kt] = make_afrag(w_hh1, H_, row, kt * 32 + quad * 8);
      }
    }
    float4 fb = make_float4(0.f, 0.f, 0.f, 0.f);
    if (w < 2) {
#pragma unroll
      for (int kt = 0; kt < 4; ++kt) a_fc[kt] = make_afrag(fc_w, H_, w * 16 + n, kt * 32 + quad * 8);
      fb = *(const float4*)(fc_b + w * 16 + quad * 4);
    }
    __syncthreads();
    int q = 0;
    half8 By[4];

    for (int t = 0; t < T_; ++t) {
      const int ck = t / CH_, s = t - ck * CH_;
      if (s == 0) {                          // chunk available?
        if (tid == 0) wait_ge(flag, ck + 1);
        __syncthreads();
        __builtin_amdgcn_fence(__ATOMIC_ACQUIRE, "agent");
        const _Float16* yp = ring + ((size_t)((ck % RING_) * CH_) * 16 + n) * 128 + quad * 8;
#pragma unroll
        for (int kt = 0; kt < 4; ++kt) By[kt] = *(const half8*)(yp + kt * 32);
      }
      // h1(t-1) fragments from LDS; FC(t-1) reuses them
      half8 Bh[4];
#pragma unroll
      for (int kt = 0; kt < 4; ++kt)
        Bh[kt] = *(const half8*)(sh_h + q * 16 * HSTR + n * HSTR + (kt * 32 + quad * 8) * 2);
      if (w < 2 && t > 0) {
        float4v af = {0.f, 0.f, 0.f, 0.f};
#pragma unroll
        for (int kt = 0; kt < 4; ++kt)
          af = __builtin_amdgcn_mfma_f32_16x16x32_f16(a_fc[kt], Bh[kt], af, 0, 0, 0);
        float* op = out + ((size_t)(t - 1) * B_ + g * 16 + n) * OUT_ + w * 16 + quad * 4;
        *(float4*)op = make_float4(af[0] + fb.x, af[1] + fb.y, af[2] + fb.z, af[3] + fb.w);
      }
      float4v accA[4] = {{0,0,0,0},{0,0,0,0},{0,0,0,0},{0,0,0,0}};
      float4v accB[4] = {{0,0,0,0},{0,0,0,0},{0,0,0,0},{0,0,0,0}};
#pragma unroll
      for (int kt = 0; kt < 4; ++kt) {
#pragma unroll
        for (int gt = 0; gt < 4; ++gt)
          accA[gt] = __builtin_amdgcn_mfma_f32_16x16x32_f16(a_h[gt][kt], Bh[kt], accA[gt], 0, 0, 0);
      }
#pragma unroll
      for (int kt = 0; kt < 4; ++kt) {
#pragma unroll
        for (int gt = 0; gt < 4; ++gt)
          accB[gt] = __builtin_amdgcn_mfma_f32_16x16x32_f16(a_i[gt][kt], By[kt], accB[gt], 0, 0, 0);
      }
      // prefetch By(t+1) within the chunk; hidden under activations
      half8 Byn[4];
      const bool pf = (s != CH_ - 1) && (t + 1 < T_);
      if (pf) {
        const _Float16* yp = ring + ((size_t)((ck % RING_) * CH_ + s + 1) * 16 + n) * 128 + quad * 8;
#pragma unroll
        for (int kt = 0; kt < 4; ++kt) Byn[kt] = *(const half8*)(yp + kt * 32);
      }
      half4v hh;
#pragma unroll
      for (int r = 0; r < 4; ++r) {
        float iv = sigm(accA[0][r] + accB[0][r]);
        float fv = sigm(accA[1][r] + accB[1][r]);
        float gv = tanh_f(accA[2][r] + accB[2][r]);
        float ov = sigm(accA[3][r] + accB[3][r]);
        c[r] = fv * c[r] + iv * gv;
        hf[r] = ov * tanh_f(c[r]);
        hh[r] = (_Float16)hf[r];
      }
      *(half4v*)(sh_h + (1 - q) * 16 * HSTR + n * HSTR + (w * 16 + quad * 4) * 2) = hh;
      __syncthreads();
      if (s == CH_ - 1 && tid == 0) {
        __builtin_amdgcn_fence(__ATOMIC_RELEASE, "agent");
        __hip_atomic_store(consumed, ck + 1, __ATOMIC_RELAXED, __HIP_MEMORY_SCOPE_AGENT);
      }
      if (pf) {
#pragma unroll
        for (int kt = 0; kt < 4; ++kt) By[kt] = Byn[kt];
      }
      q ^= 1;
    }
    // FC(T-1) from sh_h[q] = h1(T-1)
    if (w < 2) {
      float4v af = {0.f, 0.f, 0.f, 0.f};
#pragma unroll
      for (int kt = 0; kt < 4; ++kt) {
        half8 Bh = *(const half8*)(sh_h + q * 16 * HSTR + n * HSTR + (kt * 32 + quad * 8) * 2);
        af = __builtin_amdgcn_mfma_f32_16x16x32_f16(a_fc[kt], Bh, af, 0, 0, 0);
      }
      float* op = out + ((size_t)(T_ - 1) * B_ + g * 16 + n) * OUT_ + w * 16 + quad * 4;
      *(float4*)op = make_float4(af[0] + fb.x, af[1] + fb.y, af[2] + fb.z, af[3] + fb.w);
    }
    {
      float* hn = out + hn_base + (size_t)B_ * H_;
      float* cn = out + hn_base + 3 * (size_t)B_ * H_;
      size_t idx = (size_t)(g * 16 + n) * H_ + w * 16 + quad * 4;
      *(float4*)(hn + idx) = make_float4(hf[0], hf[1], hf[2], hf[3]);
      *(float4*)(cn + idx) = make_float4(c[0], c[1], c[2], c[3]);
    }
  }
}

extern "C" void kernel_launch(void* const* d_in, const int* in_sizes, int n_in,
                              void* d_out, int out_size, void* d_ws, size_t ws_size,
                              hipStream_t stream) {
  const float* x     = (const float*)d_in[0];
  const float* w_ih0 = (const float*)d_in[1];
  const float* w_hh0 = (const float*)d_in[2];
  const float* w_ih1 = (const float*)d_in[3];
  const float* w_hh1 = (const float*)d_in[4];
  const float* fc_w  = (const float*)d_in[5];
  const float* fc_b  = (const float*)d_in[6];
  char* ws = (char*)d_ws;
  ring_init<<<1, 64, 0, stream>>>((int*)(ws + RING_BYTES));
  lstm_wavefront<<<16, 512, 0, stream>>>(x, w_ih0, w_hh0, w_ih1, w_hh1,
                                         fc_w, fc_b, (float*)d_out, ws);
}

// Round 6
// 3076.934 us; speedup vs baseline: 4.0214x; 1.0551x over previous
//
#include <hip/hip_runtime.h>

#define T_ 2048
#define B_ 128
#define IN_ 64
#define H_ 128
#define OUT_ 32
#define CH_ 32          // steps per ring chunk (sync amortization)
#define RING_ 2         // chunks in flight

typedef _Float16 half8 __attribute__((ext_vector_type(8)));
typedef _Float16 half4v __attribute__((ext_vector_type(4)));
typedef float float4v __attribute__((ext_vector_type(4)));

#define XSTR 144        // bytes per batch-row, x staging
#define HSTR 272        // bytes per batch-row, h staging
#define GRP_ELEMS ((size_t)RING_ * CH_ * 16 * 128)
#define RING_BYTES ((size_t)8 * GRP_ELEMS * 2)

// fast activations: v_exp_f32 + v_rcp_f32
__device__ __forceinline__ float sigm(float x) {
  return __builtin_amdgcn_rcpf(1.0f + __expf(-x));
}
__device__ __forceinline__ float tanh_f(float x) {
  return fmaf(-2.0f, __builtin_amdgcn_rcpf(1.0f + __expf(2.0f * x)), 1.0f);
}

__device__ __forceinline__ half8 make_afrag(const float* __restrict__ W, int K, int row, int col) {
  const float* p = W + (size_t)row * K + col;
  float4 a = *(const float4*)p;
  float4 b = *(const float4*)(p + 4);
  half8 h;
  h[0]=(_Float16)a.x; h[1]=(_Float16)a.y; h[2]=(_Float16)a.z; h[3]=(_Float16)a.w;
  h[4]=(_Float16)b.x; h[5]=(_Float16)b.y; h[6]=(_Float16)b.z; h[7]=(_Float16)b.w;
  return h;
}

__device__ __forceinline__ void wait_ge(int* p, int want) {
  while (__hip_atomic_load(p, __ATOMIC_RELAXED, __HIP_MEMORY_SCOPE_AGENT) < want)
    __builtin_amdgcn_s_sleep(2);
}

__global__ void ring_init(int* f) { if (threadIdx.x < 16) f[threadIdx.x] = 0; }

__global__ __launch_bounds__(512) void lstm_wavefront(
    const float* __restrict__ x, const float* __restrict__ w_ih0,
    const float* __restrict__ w_hh0, const float* __restrict__ w_ih1,
    const float* __restrict__ w_hh1, const float* __restrict__ fc_w,
    const float* __restrict__ fc_b, float* __restrict__ out, char* __restrict__ ws)
{
  const int tid  = threadIdx.x, lane = tid & 63, w = tid >> 6;
  const int quad = lane >> 4, n = lane & 15;
  const int g = blockIdx.x & 7, layer = blockIdx.x >> 3;  // L0/L1 pair per XCD
  _Float16* ring = (_Float16*)ws + (size_t)g * GRP_ELEMS;
  int* flag     = (int*)(ws + RING_BYTES) + g;        // chunks produced by L0
  int* consumed = (int*)(ws + RING_BYTES) + 8 + g;    // chunks consumed by L1

  __shared__ char sh_x[2 * 16 * XSTR];
  __shared__ char sh_h[2 * 16 * HSTR];

  const size_t hn_base = (size_t)T_ * B_ * OUT_;
  float4v c = {0.f, 0.f, 0.f, 0.f};
  float hf[4] = {0.f, 0.f, 0.f, 0.f};

  for (int i = tid; i < 2 * 16 * HSTR / 4; i += 512) ((unsigned*)sh_h)[i] = 0u;

  if (layer == 0) {
    // ================= LAYER 0 (producer) =================
    half8 a_x[4][2], a_h[4][4];
#pragma unroll
    for (int gt = 0; gt < 4; ++gt) {
      const int row = gt * H_ + w * 16 + n;
#pragma unroll
      for (int kt = 0; kt < 2; ++kt) a_x[gt][kt] = make_afrag(w_ih0, IN_, row, kt * 32 + quad * 8);
#pragma unroll
      for (int kt = 0; kt < 4; ++kt) a_h[gt][kt] = make_afrag(w_hh0, H_, row, kt * 32 + quad * 8);
    }
    {
      const int xn = tid >> 5, xk = (tid & 31) * 2;
      float2 xv = *(const float2*)(x + ((size_t)0 * B_ + g * 16 + xn) * IN_ + xk);
      _Float16* d = (_Float16*)(sh_x + xn * XSTR + xk * 2);
      d[0] = (_Float16)xv.x; d[1] = (_Float16)xv.y;
    }
    __syncthreads();
    int p = 0;
    half4v hh_def = {0, 0, 0, 0};

    for (int t = 0; t < T_; ++t) {
      const int ck = t >> 5, s = t & (CH_ - 1);
      if (s == 0 && ck >= RING_) wait_ge(consumed, ck - 1);  // all threads poll
      // deferred ring store of y0(t-1): completes during this step's compute
      if (t > 0) {
        const int tp = t - 1;
        *(half4v*)(ring + ((size_t)(((tp >> 5) % RING_) * CH_ + (tp & (CH_ - 1))) * 16 + n) * 128
                   + w * 16 + quad * 4) = hh_def;
      }
      const int xn = tid >> 5, xk = (tid & 31) * 2;
      float2 xv = make_float2(0.f, 0.f);
      if (t + 1 < T_) xv = *(const float2*)(x + ((size_t)(t + 1) * B_ + g * 16 + xn) * IN_ + xk);

      // shared B fragments (read once, reused by all 4 gates)
      half8 Bx[2], Bh[4];
#pragma unroll
      for (int kt = 0; kt < 2; ++kt)
        Bx[kt] = *(const half8*)(sh_x + (t & 1) * 16 * XSTR + n * XSTR + (kt * 32 + quad * 8) * 2);
#pragma unroll
      for (int kt = 0; kt < 4; ++kt)
        Bh[kt] = *(const half8*)(sh_h + p * 16 * HSTR + n * HSTR + (kt * 32 + quad * 8) * 2);

      // gate-major: chained MFMA -> immediate activation (trans overlaps next gate's MFMA)
      float4 act[4];
#pragma unroll
      for (int gt = 0; gt < 4; ++gt) {
        float4v acc = {0.f, 0.f, 0.f, 0.f};
        acc = __builtin_amdgcn_mfma_f32_16x16x32_f16(a_x[gt][0], Bx[0], acc, 0, 0, 0);
        acc = __builtin_amdgcn_mfma_f32_16x16x32_f16(a_x[gt][1], Bx[1], acc, 0, 0, 0);
#pragma unroll
        for (int kt = 0; kt < 4; ++kt)
          acc = __builtin_amdgcn_mfma_f32_16x16x32_f16(a_h[gt][kt], Bh[kt], acc, 0, 0, 0);
        if (gt == 2) act[gt] = make_float4(tanh_f(acc[0]), tanh_f(acc[1]), tanh_f(acc[2]), tanh_f(acc[3]));
        else         act[gt] = make_float4(sigm(acc[0]), sigm(acc[1]), sigm(acc[2]), sigm(acc[3]));
      }
      half4v hh;
      {
        const float* iv = &act[0].x; const float* fv = &act[1].x;
        const float* gv = &act[2].x; const float* ov = &act[3].x;
#pragma unroll
        for (int r = 0; r < 4; ++r) {
          c[r] = fv[r] * c[r] + iv[r] * gv[r];
          hf[r] = ov[r] * tanh_f(c[r]);
          hh[r] = (_Float16)hf[r];
        }
      }
      *(half4v*)(sh_h + (1 - p) * 16 * HSTR + n * HSTR + (w * 16 + quad * 4) * 2) = hh;
      hh_def = hh;
      if (t + 1 < T_) {
        _Float16* d = (_Float16*)(sh_x + ((t + 1) & 1) * 16 * XSTR + xn * XSTR + xk * 2);
        d[0] = (_Float16)xv.x; d[1] = (_Float16)xv.y;
      }
      __syncthreads();
      if (tid == 0 && s == 0 && t > 0) {     // chunks 0..ck-1 fully stored+drained
        __builtin_amdgcn_fence(__ATOMIC_RELEASE, "agent");
        __hip_atomic_store(flag, ck, __ATOMIC_RELAXED, __HIP_MEMORY_SCOPE_AGENT);
      }
      p ^= 1;
    }
    // epilogue: final y0(T-1) + flag T_/CH_
    {
      const int tp = T_ - 1;
      *(half4v*)(ring + ((size_t)(((tp >> 5) % RING_) * CH_ + (tp & (CH_ - 1))) * 16 + n) * 128
                 + w * 16 + quad * 4) = hh_def;
    }
    __syncthreads();
    if (tid == 0) {
      __builtin_amdgcn_fence(__ATOMIC_RELEASE, "agent");
      __hip_atomic_store(flag, T_ / CH_, __ATOMIC_RELAXED, __HIP_MEMORY_SCOPE_AGENT);
    }
    {
      float* hn = out + hn_base;
      float* cn = out + hn_base + 2 * (size_t)B_ * H_;
      size_t idx = (size_t)(g * 16 + n) * H_ + w * 16 + quad * 4;
      *(float4*)(hn + idx) = make_float4(hf[0], hf[1], hf[2], hf[3]);
      *(float4*)(cn + idx) = make_float4(c[0], c[1], c[2], c[3]);
    }
  } else {
    // ================= LAYER 1 + FC (consumer) =================
    half8 a_i[4][4], a_h[4][4], a_fc[4];
#pragma unroll
    for (int gt = 0; gt < 4; ++gt) {
      const int row = gt * H_ + w * 16 + n;
#pragma unroll
      for (int kt = 0; kt < 4; ++kt) {
        a_i[gt][kt] = make_afrag(w_ih1, H_, row, kt * 32 + quad * 8);
        a_h[gt][kt] = make_afrag(w_hh1, H_, row, kt * 32 + quad * 8);
      }
    }
    float4 fb = make_float4(0.f, 0.f, 0.f, 0.f);
    if (w < 2) {
#pragma unroll
      for (int kt = 0; kt < 4; ++kt) a_fc[kt] = make_afrag(fc_w, H_, w * 16 + n, kt * 32 + quad * 8);
      fb = *(const float4*)(fc_b + w * 16 + quad * 4);
    }
    __syncthreads();
    int q = 0;
    half8 By[4];

    for (int t = 0; t < T_; ++t) {
      const int ck = t >> 5, s = t & (CH_ - 1);
      if (s == 0) {                          // chunk available? all threads poll
        wait_ge(flag, ck + 1);
        __builtin_amdgcn_fence(__ATOMIC_ACQUIRE, "agent");
        const _Float16* yp = ring + ((size_t)((ck % RING_) * CH_) * 16 + n) * 128 + quad * 8;
#pragma unroll
        for (int kt = 0; kt < 4; ++kt) By[kt] = *(const half8*)(yp + kt * 32);
      }
      // h1(t-1) fragments from LDS; FC(t-1) reuses them
      half8 Bh[4];
#pragma unroll
      for (int kt = 0; kt < 4; ++kt)
        Bh[kt] = *(const half8*)(sh_h + q * 16 * HSTR + n * HSTR + (kt * 32 + quad * 8) * 2);
      if (w < 2 && t > 0) {
        float4v af = {0.f, 0.f, 0.f, 0.f};
#pragma unroll
        for (int kt = 0; kt < 4; ++kt)
          af = __builtin_amdgcn_mfma_f32_16x16x32_f16(a_fc[kt], Bh[kt], af, 0, 0, 0);
        float* op = out + ((size_t)(t - 1) * B_ + g * 16 + n) * OUT_ + w * 16 + quad * 4;
        *(float4*)op = make_float4(af[0] + fb.x, af[1] + fb.y, af[2] + fb.z, af[3] + fb.w);
      }
      // gate-major chained MFMA -> immediate activation
      float4 act[4];
#pragma unroll
      for (int gt = 0; gt < 4; ++gt) {
        float4v acc = {0.f, 0.f, 0.f, 0.f};
#pragma unroll
        for (int kt = 0; kt < 4; ++kt)
          acc = __builtin_amdgcn_mfma_f32_16x16x32_f16(a_i[gt][kt], By[kt], acc, 0, 0, 0);
#pragma unroll
        for (int kt = 0; kt < 4; ++kt)
          acc = __builtin_amdgcn_mfma_f32_16x16x32_f16(a_h[gt][kt], Bh[kt], acc, 0, 0, 0);
        if (gt == 2) act[gt] = make_float4(tanh_f(acc[0]), tanh_f(acc[1]), tanh_f(acc[2]), tanh_f(acc[3]));
        else         act[gt] = make_float4(sigm(acc[0]), sigm(acc[1]), sigm(acc[2]), sigm(acc[3]));
      }
      // prefetch By(t+1) within the chunk; hidden under tail activations
      half8 Byn[4];
      const bool pf = (s != CH_ - 1) && (t + 1 < T_);
      if (pf) {
        const _Float16* yp = ring + ((size_t)((ck % RING_) * CH_ + s + 1) * 16 + n) * 128 + quad * 8;
#pragma unroll
        for (int kt = 0; kt < 4; ++kt) Byn[kt] = *(const half8*)(yp + kt * 32);
      }
      half4v hh;
      {
        const float* iv = &act[0].x; const float* fv = &act[1].x;
        const float* gv = &act[2].x; const float* ov = &act[3].x;
#pragma unroll
        for (int r = 0; r < 4; ++r) {
          c[r] = fv[r] * c[r] + iv[r] * gv[r];
          hf[r] = ov[r] * tanh_f(c[r]);
          hh[r] = (_Float16)hf[r];
        }
      }
      *(half4v*)(sh_h + (1 - q) * 16 * HSTR + n * HSTR + (w * 16 + quad * 4) * 2) = hh;
      __syncthreads();
      if (s == CH_ - 1 && tid == 0) {
        __builtin_amdgcn_fence(__ATOMIC_RELEASE, "agent");
        __hip_atomic_store(consumed, ck + 1, __ATOMIC_RELAXED, __HIP_MEMORY_SCOPE_AGENT);
      }
      if (pf) {
#pragma unroll
        for (int kt = 0; kt < 4; ++kt) By[kt] = Byn[kt];
      }
      q ^= 1;
    }
    // FC(T-1) from sh_h[q] = h1(T-1)
    if (w < 2) {
      float4v af = {0.f, 0.f, 0.f, 0.f};
#pragma unroll
      for (int kt = 0; kt < 4; ++kt) {
        half8 Bh = *(const half8*)(sh_h + q * 16 * HSTR + n * HSTR + (kt * 32 + quad * 8) * 2);
        af = __builtin_amdgcn_mfma_f32_16x16x32_f16(a_fc[kt], Bh, af, 0, 0, 0);
      }
      float* op = out + ((size_t)(T_ - 1) * B_ + g * 16 + n) * OUT_ + w * 16 + quad * 4;
      *(float4*)op = make_float4(af[0] + fb.x, af[1] + fb.y, af[2] + fb.z, af[3] + fb.w);
    }
    {
      float* hn = out + hn_base + (size_t)B_ * H_;
      float* cn = out + hn_base + 3 * (size_t)B_ * H_;
      size_t idx = (size_t)(g * 16 + n) * H_ + w * 16 + quad * 4;
      *(float4*)(hn + idx) = make_float4(hf[0], hf[1], hf[2], hf[3]);
      *(float4*)(cn + idx) = make_float4(c[0], c[1], c[2], c[3]);
    }
  }
}

extern "C" void kernel_launch(void* const* d_in, const int* in_sizes, int n_in,
                              void* d_out, int out_size, void* d_ws, size_t ws_size,
                              hipStream_t stream) {
  const float* x     = (const float*)d_in[0];
  const float* w_ih0 = (const float*)d_in[1];
  const float* w_hh0 = (const float*)d_in[2];
  const float* w_ih1 = (const float*)d_in[3];
  const float* w_hh1 = (const float*)d_in[4];
  const float* fc_w  = (const float*)d_in[5];
  const float* fc_b  = (const float*)d_in[6];
  char* ws = (char*)d_ws;
  ring_init<<<1, 64, 0, stream>>>((int*)(ws + RING_BYTES));
  lstm_wavefront<<<16, 512, 0, stream>>>(x, w_ih0, w_hh0, w_ih1, w_hh1,
                                         fc_w, fc_b, (float*)d_out, ws);
}